// Round 4
// baseline (1302.395 us; speedup 1.0000x reference)
//
#include <hip/hip_runtime.h>

#define NFFT 16384
#define LSIG 8192
#define NH   1024
#define NTH  1024
#define LDSN (NFFT + (NFFT >> 5))   // 16896 floats per plane (pad every 32)

__device__ __forceinline__ int PADI(int i) { return i + (i >> 5); }

struct cplx { float x, y; };
__device__ __forceinline__ cplx cadd(cplx a, cplx b){ return {a.x+b.x, a.y+b.y}; }
__device__ __forceinline__ cplx csub(cplx a, cplx b){ return {a.x-b.x, a.y-b.y}; }
__device__ __forceinline__ cplx cmul(cplx a, cplx b){ return {a.x*b.x - a.y*b.y, a.x*b.y + a.y*b.x}; }

// w32[k] = (cos(2*pi*k/32), sin(2*pi*k/32)), k=0..15
constexpr float W32C[16] = {
  1.0f, 0.9807852804f, 0.9238795325f, 0.8314696123f,
  0.7071067812f, 0.5555702330f, 0.3826834324f, 0.1950903220f,
  0.0f, -0.1950903220f, -0.3826834324f, -0.5555702330f,
  -0.7071067812f, -0.8314696123f, -0.9238795325f, -0.9807852804f };
constexpr float W32S[16] = {
  0.0f, 0.1950903220f, 0.3826834324f, 0.5555702330f,
  0.7071067812f, 0.8314696123f, 0.9238795325f, 0.9807852804f,
  1.0f, 0.9807852804f, 0.9238795325f, 0.8314696123f,
  0.7071067812f, 0.5555702330f, 0.3826834324f, 0.1950903220f };
constexpr int BR3[8] = {0,4,2,6,1,5,3,7};
constexpr int BR4[16] = {0,8,4,12,2,10,6,14,1,9,5,13,3,11,7,15};

// One radix-2 pass with COMPILE-TIME span SP -> all indices constant after
// unroll -> arrays stay in registers (rule #20).
template<int N, int SP, bool INV>
__device__ __forceinline__ void fft_pass(cplx* z) {
  #pragma unroll
  for (int b = 0; b < N; b += 2*SP) {
    #pragma unroll
    for (int r = 0; r < SP; ++r) {
      const int kk = r * (16 / SP);        // W_{2SP}^r = W32^{r*16/SP}, SP<=16
      if (!INV) {
        cplx u = z[b+r], v = z[b+r+SP];
        z[b+r] = cadd(u, v);
        cplx d = csub(u, v);
        z[b+r+SP] = cmul(d, cplx{W32C[kk], -W32S[kk]});
      } else {
        cplx t0 = z[b+r], t1 = z[b+r+SP];
        cplx w = cmul(t1, cplx{W32C[kk], W32S[kk]});   // conj twiddle
        z[b+r]    = cadd(t0, w);
        z[b+r+SP] = csub(t0, w);
      }
    }
  }
}

// Forward: natural -> bit-reversed (DIF). Inverse: exact mirror, no 1/N.
template<int N, bool INV>
__device__ __forceinline__ void fft_regs(cplx* z) {
  if constexpr (!INV) {
    if constexpr (N >= 32) fft_pass<N,16,false>(z);
    if constexpr (N >= 16) fft_pass<N, 8,false>(z);
    if constexpr (N >=  8) fft_pass<N, 4,false>(z);
    if constexpr (N >=  4) fft_pass<N, 2,false>(z);
    fft_pass<N,1,false>(z);
  } else {
    fft_pass<N,1,true>(z);
    if constexpr (N >=  4) fft_pass<N, 2,true>(z);
    if constexpr (N >=  8) fft_pass<N, 4,true>(z);
    if constexpr (N >= 16) fft_pass<N, 8,true>(z);
    if constexpr (N >= 32) fft_pass<N,16,true>(z);
  }
}

// LDS radix-8 stage (sub-problem M = 8*S). 2 butterflies/thread at NTH=1024.
template<int S, bool INV>
__device__ __forceinline__ void stage8(float* sre, float* sim, int tid) {
  const float ang1 = (INV ? 2.0f : -2.0f) * 3.14159265358979f / (float)(8 * S);
  #pragma unroll
  for (int it = 0; it < (NFFT/8)/NTH; ++it) {
    int bf = tid + it * NTH;                    // 0..2047
    int q = bf / S;
    int r = bf - q * S;
    int base = q * (8 * S) + r;
    float sn, cs;
    __sincosf(ang1 * (float)r, &sn, &cs);
    cplx w1 = {cs, sn};
    cplx wp[8];
    wp[0] = {1.0f, 0.0f};
    #pragma unroll
    for (int m = 1; m < 8; ++m) wp[m] = cmul(wp[m-1], w1);

    cplx a[8];
    if (!INV) {
      #pragma unroll
      for (int j = 0; j < 8; ++j) { int idx = PADI(base + j*S); a[j] = {sre[idx], sim[idx]}; }
      fft_regs<8,false>(a);                     // a[p] = B[BR3[p]]
      #pragma unroll
      for (int p = 0; p < 8; ++p) {
        const int m = BR3[p];
        cplx o = cmul(a[p], wp[m]);
        int idx = PADI(base + m*S);
        sre[idx] = o.x; sim[idx] = o.y;
      }
    } else {
      #pragma unroll
      for (int p = 0; p < 8; ++p) {
        const int m = BR3[p];
        int idx = PADI(base + m*S);
        cplx v = {sre[idx], sim[idx]};
        a[p] = cmul(v, wp[m]);                  // strip forward twiddle
      }
      fft_regs<8,true>(a);
      #pragma unroll
      for (int j = 0; j < 8; ++j) { int idx = PADI(base + j*S); sre[idx] = a[j].x; sim[idx] = a[j].y; }
    }
  }
}

// LDS radix-16 stage, S=16 (sub-problem 256). 1 butterfly/thread at NTH=1024.
template<bool INV>
__device__ __forceinline__ void stage16(float* sre, float* sim, int tid) {
  const float ang1 = (INV ? 2.0f : -2.0f) * 3.14159265358979f / 256.0f;
  int q = tid >> 4;
  int r = tid & 15;
  int base = q * 256 + r;
  float sn, cs;
  __sincosf(ang1 * (float)r, &sn, &cs);
  cplx w1 = {cs, sn};
  cplx wp[16];
  wp[0] = {1.0f, 0.0f};
  #pragma unroll
  for (int m = 1; m < 16; ++m) wp[m] = cmul(wp[m-1], w1);

  cplx a[16];
  if (!INV) {
    #pragma unroll
    for (int j = 0; j < 16; ++j) { int idx = PADI(base + j*16); a[j] = {sre[idx], sim[idx]}; }
    fft_regs<16,false>(a);                      // a[p] = B[BR4[p]]
    #pragma unroll
    for (int p = 0; p < 16; ++p) {
      const int m = BR4[p];
      cplx o = cmul(a[p], wp[m]);
      int idx = PADI(base + m*16);
      sre[idx] = o.x; sim[idx] = o.y;
    }
  } else {
    #pragma unroll
    for (int p = 0; p < 16; ++p) {
      const int m = BR4[p];
      int idx = PADI(base + m*16);
      cplx v = {sre[idx], sim[idx]};
      a[p] = cmul(v, wp[m]);
    }
    fft_regs<16,true>(a);
    #pragma unroll
    for (int j = 0; j < 16; ++j) { int idx = PADI(base + j*16); sre[idx] = a[j].x; sim[idx] = a[j].y; }
  }
}

// One block per h (grid=1024). K FFT once, then loop the 4 batch-pairs.
// Peak live regs ~90 (z[16]+kreg[16]+temps) -> no spill under a 128 cap.
__global__ __launch_bounds__(NTH)
void fftconv_kernel(const float* __restrict__ u, const float* __restrict__ kin,
                    float* __restrict__ out) {
  __shared__ float sre[LDSN];
  __shared__ float sim[LDSN];
  const int tid = threadIdx.x;
  const int h = blockIdx.x;

  // ---------------- K row FFT (spectrum kept in registers, pre-scaled) -------
  const float* krow = kin + (size_t)h * LSIG;
  #pragma unroll
  for (int c = 0; c < 2; ++c) {
    int i0 = (c * NTH + tid) * 4;
    float4 v = *reinterpret_cast<const float4*>(krow + i0);
    int p0 = PADI(i0);
    sre[p0+0]=v.x; sre[p0+1]=v.y; sre[p0+2]=v.z; sre[p0+3]=v.w;
    sim[p0+0]=0.f; sim[p0+1]=0.f; sim[p0+2]=0.f; sim[p0+3]=0.f;
    int p1 = PADI(i0 + LSIG);
    sre[p1+0]=0.f; sre[p1+1]=0.f; sre[p1+2]=0.f; sre[p1+3]=0.f;
    sim[p1+0]=0.f; sim[p1+1]=0.f; sim[p1+2]=0.f; sim[p1+3]=0.f;
  }
  __syncthreads();
  stage8<2048,false>(sre, sim, tid); __syncthreads();
  stage8< 256,false>(sre, sim, tid); __syncthreads();
  stage16<false>(sre, sim, tid);     __syncthreads();

  cplx kreg[16];
  {
    cplx z[16];
    int p0 = PADI(tid * 16);        // 16 elems are contiguous (no pad crossing)
    #pragma unroll
    for (int e = 0; e < 16; ++e) z[e] = {sre[p0+e], sim[p0+e]};
    fft_regs<16,false>(z);
    const float scl = 1.0f / (float)NFFT;
    #pragma unroll
    for (int e = 0; e < 16; ++e) kreg[e] = {z[e].x * scl, z[e].y * scl};
  }

  for (int pr = 0; pr < 4; ++pr) {
    __syncthreads();                // LDS safe to overwrite

    const float* u0 = u + ((size_t)(2*pr) * NH + h) * LSIG;
    const float* u1 = u0 + (size_t)NH * LSIG;
    #pragma unroll
    for (int c = 0; c < 2; ++c) {
      int i0 = (c * NTH + tid) * 4;
      float4 a = *reinterpret_cast<const float4*>(u0 + i0);
      float4 b = *reinterpret_cast<const float4*>(u1 + i0);
      int p0 = PADI(i0);
      sre[p0+0]=a.x; sre[p0+1]=a.y; sre[p0+2]=a.z; sre[p0+3]=a.w;
      sim[p0+0]=b.x; sim[p0+1]=b.y; sim[p0+2]=b.z; sim[p0+3]=b.w;
      int p1 = PADI(i0 + LSIG);
      sre[p1+0]=0.f; sre[p1+1]=0.f; sre[p1+2]=0.f; sre[p1+3]=0.f;
      sim[p1+0]=0.f; sim[p1+1]=0.f; sim[p1+2]=0.f; sim[p1+3]=0.f;
    }
    __syncthreads();
    stage8<2048,false>(sre, sim, tid); __syncthreads();
    stage8< 256,false>(sre, sim, tid); __syncthreads();
    stage16<false>(sre, sim, tid);     __syncthreads();

    {   // fused: reg-16 FFT, pointwise multiply (scrambled order), reg-16 inv
      cplx z[16];
      int p0 = PADI(tid * 16);
      #pragma unroll
      for (int e = 0; e < 16; ++e) z[e] = {sre[p0+e], sim[p0+e]};
      fft_regs<16,false>(z);
      #pragma unroll
      for (int e = 0; e < 16; ++e) z[e] = cmul(z[e], kreg[e]);
      fft_regs<16,true>(z);
      #pragma unroll
      for (int e = 0; e < 16; ++e) { sre[p0+e] = z[e].x; sim[p0+e] = z[e].y; }
    }
    __syncthreads();
    stage16<true>(sre, sim, tid);     __syncthreads();
    stage8< 256,true>(sre, sim, tid); __syncthreads();
    stage8<2048,true>(sre, sim, tid); __syncthreads();

    float* o0 = out + ((size_t)(2*pr) * NH + h) * LSIG;
    float* o1 = o0 + (size_t)NH * LSIG;
    #pragma unroll
    for (int c = 0; c < 2; ++c) {
      int i0 = (c * NTH + tid) * 4;
      int p0 = PADI(i0);
      float4 a = {sre[p0], sre[p0+1], sre[p0+2], sre[p0+3]};
      float4 b = {sim[p0], sim[p0+1], sim[p0+2], sim[p0+3]};
      *reinterpret_cast<float4*>(o0 + i0) = a;
      *reinterpret_cast<float4*>(o1 + i0) = b;
    }
  }
}

extern "C" void kernel_launch(void* const* d_in, const int* in_sizes, int n_in,
                              void* d_out, int out_size, void* d_ws, size_t ws_size,
                              hipStream_t stream) {
  (void)in_sizes; (void)n_in; (void)d_ws; (void)ws_size; (void)out_size;
  const float* u = (const float*)d_in[0];
  const float* k = (const float*)d_in[1];
  float* out = (float*)d_out;
  dim3 grid(NH), block(NTH);
  hipLaunchKernelGGL(fftconv_kernel, grid, block, 0, stream, u, k, out);
}